// Round 5
// baseline (691.903 us; speedup 1.0000x reference)
//
#include <hip/hip_runtime.h>
#include <hip/hip_bf16.h>
#include <math.h>

#define N_NODES 50000
#define N_EDGES 800000
#define IN_SIZE 256
#define OUT_SIZE 128
#define EDGE_DIM 64
#define NCAT 640   // [q:0-127 | k:128-255 | v:256-383 | sk:384-511 | q2:512-575 | pad:576-639]

#define SCAN_B 256
#define NBLK ((N_NODES + SCAN_B - 1) / SCAN_B)   // 196

typedef __attribute__((ext_vector_type(8))) short short8;
typedef __attribute__((ext_vector_type(4))) float floatx4;

#define GPTR(p) ((const __attribute__((address_space(1))) void*)(p))
#define LPTR(p) ((__attribute__((address_space(3))) void*)(p))

__device__ __forceinline__ unsigned short f2bf(float f) {
    unsigned int u = __float_as_uint(f);
    unsigned int r = (u + 0x7fffu + ((u >> 16) & 1u)) >> 16;  // RNE
    return (unsigned short)r;
}
__device__ __forceinline__ float bfs_to_f(unsigned short s) {
    return __uint_as_float(((unsigned int)s) << 16);
}
__device__ __forceinline__ float2 bf2_to_f2(unsigned int u) {
    float2 r;
    r.x = __uint_as_float(u << 16);
    r.y = __uint_as_float(u & 0xffff0000u);
    return r;
}

// ---------------- x -> bf16 ----------------
__global__ __launch_bounds__(256) void xcast_kernel(
    const float* __restrict__ x, unsigned short* __restrict__ xb)
{
    size_t i = ((size_t)blockIdx.x * 256 + threadIdx.x) * 4;
    float4 v = *(const float4*)(x + i);
    uint2 p;
    p.x = (unsigned int)f2bf(v.x) | ((unsigned int)f2bf(v.y) << 16);
    p.y = (unsigned int)f2bf(v.z) | ((unsigned int)f2bf(v.w) << 16);
    *(uint2*)(xb + i) = p;
}

// ---------------- WcatT (bf16, transposed [NCAT][256]) + bcat ----------------
__global__ __launch_bounds__(256) void wcat_kernel(
    const float* __restrict__ Wq, const float* __restrict__ Wk,
    const float* __restrict__ Wv, const float* __restrict__ Ws,
    const float* __restrict__ We,
    const float* __restrict__ bq, const float* __restrict__ bk,
    const float* __restrict__ bv, const float* __restrict__ bs,
    unsigned short* __restrict__ WcatT, float* __restrict__ bcat)
{
    int col = blockIdx.x;
    int kr  = threadIdx.x;
    float w = 0.f;
    if (col < 512) {
        int s = col >> 7, c = col & 127;
        const float* W = (s == 0) ? Wq : (s == 1) ? Wk : (s == 2) ? Wv : Ws;
        w = W[kr * OUT_SIZE + c];
    } else if (col < 576) {
        int d = col - 512;
        float a = 0.f;
        #pragma unroll 8
        for (int c = 0; c < OUT_SIZE; c++)
            a = fmaf(Wq[kr * OUT_SIZE + c], We[d * OUT_SIZE + c], a);
        w = a;
    }
    WcatT[(size_t)col * 256 + kr] = f2bf(w);
    if (kr == 0) {
        float b = 0.f;
        if (col < 512) {
            int s = col >> 7, c = col & 127;
            b = ((s == 0) ? bq : (s == 1) ? bk : (s == 2) ? bv : bs)[c];
        } else if (col < 576) {
            int d = col - 512;
            for (int c = 0; c < OUT_SIZE; c++)
                b = fmaf(bq[c], We[d * OUT_SIZE + c], b);
        }
        bcat[col] = b;
    }
}

// ---------------- MFMA mega GEMM, 128x128 tile, double-buffered ----------------
// grid (391, 5). seg y: 0=q(bf16) 1=k 2=v 3=sk->out(f32) 4=q2(bf16)
__global__ __launch_bounds__(256) void gemm_kernel(
    const unsigned short* __restrict__ xb,     // [N][256] bf16
    const unsigned short* __restrict__ WcatT,  // [NCAT][256] bf16
    const float* __restrict__ bcat,
    unsigned short* __restrict__ qb16, unsigned short* __restrict__ kv16,
    float* __restrict__ outbuf, unsigned short* __restrict__ q2b16)
{
    __shared__ __align__(16) unsigned short Als[2][128 * 32];
    __shared__ __align__(16) unsigned short Bls[2][128 * 32];

    const int t      = threadIdx.x;
    const int wave   = t >> 6;
    const int lane   = t & 63;
    const int quad   = lane >> 4;
    const int l16    = lane & 15;
    const int wave_m = wave & 1;
    const int wave_n = wave >> 1;

    const int m0 = blockIdx.x * 128;
    const int n0 = blockIdx.y * 128;

    floatx4 acc[4][4];
    #pragma unroll
    for (int mt = 0; mt < 4; mt++)
        #pragma unroll
        for (int nt = 0; nt < 4; nt++)
            acc[mt][nt] = (floatx4){0.f, 0.f, 0.f, 0.f};

    // staging lambda-equivalent (macro): 128 rows x 32 bf16 per matrix, 2 rounds each
#define STAGE(K0, BUF)                                                              \
    {                                                                               \
        _Pragma("unroll")                                                           \
        for (int r = 0; r < 2; r++) {                                               \
            int idx  = r * 256 + t;                                                 \
            int row  = idx >> 2;                                                    \
            int c8   = idx & 3;                                                     \
            int grow = m0 + row;                                                    \
            if (grow >= N_NODES) grow = N_NODES - 1;                                \
            const unsigned short* ga = xb + (size_t)grow * IN_SIZE + (K0) + c8 * 8; \
            __builtin_amdgcn_global_load_lds(GPTR(ga),                              \
                LPTR(Als[BUF] + (size_t)(r * 256 + wave * 64) * 8), 16, 0, 0);      \
            const unsigned short* gb = WcatT + (size_t)(n0 + row) * 256 + (K0) + c8 * 8; \
            __builtin_amdgcn_global_load_lds(GPTR(gb),                              \
                LPTR(Bls[BUF] + (size_t)(r * 256 + wave * 64) * 8), 16, 0, 0);      \
        }                                                                           \
    }

    STAGE(0, 0)
    #pragma unroll
    for (int kk = 0; kk < 8; kk++) {
        __syncthreads();
        if (kk + 1 < 8) STAGE((kk + 1) * 32, (kk + 1) & 1)
        const unsigned short* Ab = Als[kk & 1];
        const unsigned short* Bb = Bls[kk & 1];
        short8 af[4], bf[4];
        #pragma unroll
        for (int mt = 0; mt < 4; mt++)
            af[mt] = *(const short8*)(Ab + (size_t)(wave_m * 64 + mt * 16 + l16) * 32 + quad * 8);
        #pragma unroll
        for (int nt = 0; nt < 4; nt++)
            bf[nt] = *(const short8*)(Bb + (size_t)(wave_n * 64 + nt * 16 + l16) * 32 + quad * 8);
        #pragma unroll
        for (int mt = 0; mt < 4; mt++)
            #pragma unroll
            for (int nt = 0; nt < 4; nt++)
                acc[mt][nt] = __builtin_amdgcn_mfma_f32_16x16x32_bf16(af[mt], bf[nt], acc[mt][nt], 0, 0, 0);
    }
#undef STAGE

    const int seg = blockIdx.y;
    #pragma unroll
    for (int mt = 0; mt < 4; mt++) {
        #pragma unroll
        for (int r = 0; r < 4; r++) {
            int row = m0 + wave_m * 64 + mt * 16 + quad * 4 + r;
            if (row >= N_NODES) continue;
            #pragma unroll
            for (int nt = 0; nt < 4; nt++) {
                int c = n0 + wave_n * 64 + nt * 16 + l16;
                float val = acc[mt][nt][r] + bcat[c];
                if (seg == 0)      qb16[(size_t)row * OUT_SIZE + c] = f2bf(val);
                else if (seg == 1) kv16[(size_t)row * 256 + (c - 128)] = f2bf(val);
                else if (seg == 2) kv16[(size_t)row * 256 + 128 + (c - 256)] = f2bf(val);
                else if (seg == 3) outbuf[(size_t)row * OUT_SIZE + (c - 384)] = val;
                else if (c < 576)  q2b16[(size_t)row * EDGE_DIM + (c - 512)] = f2bf(val);
            }
        }
    }
}

// ---------------- CSR build ----------------
__global__ __launch_bounds__(256) void hist_kernel(
    const int* __restrict__ ei, int* __restrict__ counts)
{
    int e = blockIdx.x * 256 + threadIdx.x;
    if (e >= N_EDGES) return;
    atomicAdd(&counts[ei[N_EDGES + e]], 1);
}

__global__ __launch_bounds__(SCAN_B) void scan1_kernel(
    const int* __restrict__ counts, int* __restrict__ incl, int* __restrict__ bsum)
{
    __shared__ int tmp[SCAN_B];
    int i = blockIdx.x * SCAN_B + threadIdx.x;
    int val = (i < N_NODES) ? counts[i] : 0;
    tmp[threadIdx.x] = val;
    __syncthreads();
    for (int off = 1; off < SCAN_B; off <<= 1) {
        int t = (threadIdx.x >= off) ? tmp[threadIdx.x - off] : 0;
        __syncthreads();
        tmp[threadIdx.x] += t;
        __syncthreads();
    }
    if (i < N_NODES) incl[i] = tmp[threadIdx.x];
    if (threadIdx.x == SCAN_B - 1) bsum[blockIdx.x] = tmp[SCAN_B - 1];
}

__global__ __launch_bounds__(SCAN_B) void scan2_kernel(int* __restrict__ bsum)
{
    __shared__ int tmp[SCAN_B];
    int val = (threadIdx.x < NBLK) ? bsum[threadIdx.x] : 0;
    tmp[threadIdx.x] = val;
    __syncthreads();
    for (int off = 1; off < SCAN_B; off <<= 1) {
        int t = (threadIdx.x >= off) ? tmp[threadIdx.x - off] : 0;
        __syncthreads();
        tmp[threadIdx.x] += t;
        __syncthreads();
    }
    if (threadIdx.x < NBLK) bsum[threadIdx.x] = tmp[threadIdx.x];
}

__global__ __launch_bounds__(SCAN_B) void scan3_kernel(
    const int* __restrict__ incl, const int* __restrict__ bsum,
    const int* __restrict__ counts, int* __restrict__ rowptr, int* __restrict__ cursor)
{
    int i = blockIdx.x * SCAN_B + threadIdx.x;
    if (i >= N_NODES) return;
    int off = (blockIdx.x == 0) ? 0 : bsum[blockIdx.x - 1];
    int inc = incl[i] + off;
    rowptr[i + 1] = inc;
    cursor[i] = inc - counts[i];
    if (i == 0) rowptr[0] = 0;
}

// ---------------- scatter: CSR src list + counting-sorted bf16 edge_attr ----------------
__global__ __launch_bounds__(256) void scatter_kernel(
    const int* __restrict__ ei, const float* __restrict__ ea,
    int* __restrict__ cursor, int* __restrict__ csr_src,
    unsigned short* __restrict__ eperm)
{
    int e = blockIdx.x * 256 + threadIdx.x;
    if (e >= N_EDGES) return;
    int dst = ei[N_EDGES + e];
    int pos = atomicAdd(&cursor[dst], 1);
    csr_src[pos] = ei[e];
    const float4* s4 = (const float4*)(ea + (size_t)e * EDGE_DIM);
    ushort4* d4 = (ushort4*)(eperm + (size_t)pos * EDGE_DIM);
    #pragma unroll
    for (int j = 0; j < 16; j++) {
        float4 f = s4[j];
        ushort4 u;
        u.x = f2bf(f.x); u.y = f2bf(f.y); u.z = f2bf(f.z); u.w = f2bf(f.w);
        d4[j] = u;
    }
}

// ---------------- fused per-dst-node ----------------
__global__ __launch_bounds__(256) void fused_kernel(
    const int* __restrict__ rowptr, const int* __restrict__ csr_src,
    const unsigned int* __restrict__ qb32,   // bf16x2 view [N][64]
    const unsigned int* __restrict__ kv32,   // [N][128]: k=0..63, v=64..127
    const unsigned short* __restrict__ q2b,  // [N][64]
    const unsigned short* __restrict__ eperm,// [E][64] csr-ordered
    const float* __restrict__ We, const float* __restrict__ be,
    float* __restrict__ out)                 // holds skip, rewritten with result
{
    int node = blockIdx.x * 4 + (threadIdx.x >> 6);
    if (node >= N_NODES) return;
    int lane = threadIdx.x & 63;
    int beg = rowptr[node];
    int end = rowptr[node + 1];

    float2 qv  = bf2_to_f2(qb32[(size_t)node * 64 + lane]);
    float  q2v = bfs_to_f(q2b[(size_t)node * EDGE_DIM + lane]);
    float2 bev = ((const float2*)be)[lane];

    float qbv = qv.x * bev.x + qv.y * bev.y;
    #pragma unroll
    for (int off = 32; off > 0; off >>= 1) qbv += __shfl_xor(qbv, off);

    const float scale = 0.08838834764831845f;  // 1/sqrt(128)
    float m = -INFINITY, l = 0.f;
    float ax = 0.f, ay = 0.f, a2 = 0.f;

    int i = beg;
    for (; i + 1 < end; i += 2) {
        int s1 = csr_src[i];
        int s2 = csr_src[i + 1];
        float2 k1 = bf2_to_f2(kv32[(size_t)s1 * 128 + lane]);
        float2 k2 = bf2_to_f2(kv32[(size_t)s2 * 128 + lane]);
        float2 v1 = bf2_to_f2(kv32[(size_t)s1 * 128 + 64 + lane]);
        float2 v2 = bf2_to_f2(kv32[(size_t)s2 * 128 + 64 + lane]);
        float ea1 = bfs_to_f(eperm[(size_t)i * EDGE_DIM + lane]);
        float ea2 = bfs_to_f(eperm[(size_t)(i + 1) * EDGE_DIM + lane]);
        float p1 = qv.x * k1.x + qv.y * k1.y + q2v * ea1;
        float p2 = qv.x * k2.x + qv.y * k2.y + q2v * ea2;
        #pragma unroll
        for (int off = 32; off > 0; off >>= 1) p1 += __shfl_xor(p1, off);
        #pragma unroll
        for (int off = 32; off > 0; off >>= 1) p2 += __shfl_xor(p2, off);
        float s1v = (p1 + qbv) * scale;
        float s2v = (p2 + qbv) * scale;
        float mn = fmaxf(m, fmaxf(s1v, s2v));
        float sc  = __expf(m - mn);
        float pe1 = __expf(s1v - mn);
        float pe2 = __expf(s2v - mn);
        l  = l * sc + pe1 + pe2;
        ax = fmaf(ax, sc, fmaf(pe1, v1.x, pe2 * v2.x));
        ay = fmaf(ay, sc, fmaf(pe1, v1.y, pe2 * v2.y));
        a2 = fmaf(a2, sc, fmaf(pe1, ea1, pe2 * ea2));
        m = mn;
    }
    if (i < end) {
        int s1 = csr_src[i];
        float2 k1 = bf2_to_f2(kv32[(size_t)s1 * 128 + lane]);
        float2 v1 = bf2_to_f2(kv32[(size_t)s1 * 128 + 64 + lane]);
        float ea1 = bfs_to_f(eperm[(size_t)i * EDGE_DIM + lane]);
        float p1 = qv.x * k1.x + qv.y * k1.y + q2v * ea1;
        #pragma unroll
        for (int off = 32; off > 0; off >>= 1) p1 += __shfl_xor(p1, off);
        float s1v = (p1 + qbv) * scale;
        float mn = fmaxf(m, s1v);
        float sc  = __expf(m - mn);
        float pe1 = __expf(s1v - mn);
        l  = l * sc + pe1;
        ax = fmaf(ax, sc, pe1 * v1.x);
        ay = fmaf(ay, sc, pe1 * v1.y);
        a2 = fmaf(a2, sc, pe1 * ea1);
        m = mn;
    }

    float inv  = 1.f / (l + 1e-16f);
    float aggA = l * inv;
    ax *= inv; ay *= inv; a2 *= inv;

    float2 skv = ((const float2*)out)[(size_t)node * 64 + lane];  // skip from GEMM
    float ox = ax + aggA * bev.x + skv.x;
    float oy = ay + aggA * bev.y + skv.y;
    #pragma unroll 8
    for (int d = 0; d < EDGE_DIM; d++) {
        float g = __shfl(a2, d);
        float2 w = ((const float2*)We)[(size_t)d * 64 + lane];
        ox = fmaf(g, w.x, ox);
        oy = fmaf(g, w.y, oy);
    }
    ox = (ox > 0.f) ? ox : (__expf(ox) - 1.f);
    oy = (oy > 0.f) ? oy : (__expf(oy) - 1.f);
    ((float2*)out)[(size_t)node * 64 + lane] = make_float2(ox, oy);
}

extern "C" void kernel_launch(void* const* d_in, const int* in_sizes, int n_in,
                              void* d_out, int out_size, void* d_ws, size_t ws_size,
                              hipStream_t stream) {
    const float* x   = (const float*)d_in[0];
    const int*   ei  = (const int*)d_in[1];
    const float* ea  = (const float*)d_in[2];
    const float* Wq  = (const float*)d_in[3];
    const float* bq  = (const float*)d_in[4];
    const float* Wk  = (const float*)d_in[5];
    const float* bk  = (const float*)d_in[6];
    const float* Wv  = (const float*)d_in[7];
    const float* bv  = (const float*)d_in[8];
    const float* We  = (const float*)d_in[9];
    const float* be  = (const float*)d_in[10];
    const float* Ws  = (const float*)d_in[11];
    const float* bs  = (const float*)d_in[12];
    float* out = (float*)d_out;

    // workspace layout (~177 MB)
    unsigned short* qb16  = (unsigned short*)d_ws;                    // 12.8 MB
    unsigned short* q2b16 = qb16  + (size_t)N_NODES * OUT_SIZE;       // 6.4 MB
    unsigned short* kv16  = q2b16 + (size_t)N_NODES * EDGE_DIM;       // 25.6 MB
    unsigned short* xb    = kv16  + (size_t)N_NODES * 256;            // 25.6 MB
    unsigned short* WcatT = xb    + (size_t)N_NODES * IN_SIZE;        // 0.33 MB
    float* bcat  = (float*)(WcatT + (size_t)NCAT * 256);              // 640 f
    int* counts  = (int*)(bcat + NCAT);
    int* incl    = counts + N_NODES;
    int* bsum    = incl + N_NODES;       // 256
    int* rowptr  = bsum + 256;           // N+1
    int* cursor  = rowptr + N_NODES + 1; // N
    int* csr_src = cursor + N_NODES;     // E
    unsigned short* eperm = (unsigned short*)(csr_src + N_EDGES);     // 102.4 MB

    hipMemsetAsync(counts, 0, (size_t)N_NODES * sizeof(int), stream);

    // CSR build + edge-attr counting sort (bf16)
    hist_kernel<<<(N_EDGES + 255) / 256, 256, 0, stream>>>(ei, counts);
    scan1_kernel<<<NBLK, SCAN_B, 0, stream>>>(counts, incl, bsum);
    scan2_kernel<<<1, SCAN_B, 0, stream>>>(bsum);
    scan3_kernel<<<NBLK, SCAN_B, 0, stream>>>(incl, bsum, counts, rowptr, cursor);
    scatter_kernel<<<(N_EDGES + 255) / 256, 256, 0, stream>>>(ei, ea, cursor, csr_src, eperm);

    // bf16 conversions / weights
    xcast_kernel<<<(N_NODES * IN_SIZE / 4 + 255) / 256, 256, 0, stream>>>(x, xb);
    wcat_kernel<<<NCAT, 256, 0, stream>>>(Wq, Wk, Wv, Ws, We, bq, bk, bv, bs, WcatT, bcat);

    // MFMA mega GEMM (skip segment lands directly in d_out)
    dim3 gG((N_NODES + 127) / 128, 5);
    gemm_kernel<<<gG, 256, 0, stream>>>(xb, WcatT, bcat, qb16, kv16, out, q2b16);

    // fused edge phase + epilogue
    fused_kernel<<<(N_NODES + 3) / 4, 256, 0, stream>>>(
        rowptr, csr_src, (const unsigned int*)qb16, (const unsigned int*)kv16,
        q2b16, eperm, We, be, out);
}

// Round 6
// 648.353 us; speedup vs baseline: 1.0672x; 1.0672x over previous
//
#include <hip/hip_runtime.h>
#include <hip/hip_bf16.h>
#include <math.h>

#define N_NODES 50000
#define N_EDGES 800000
#define IN_SIZE 256
#define OUT_SIZE 128
#define EDGE_DIM 64
#define NCAT 640   // [q:0-127 | k:128-255 | v:256-383 | sk:384-511 | q2:512-575 | pad]

#define SCAN_B 256
#define NBLK ((N_NODES + SCAN_B - 1) / SCAN_B)   // 196

typedef __attribute__((ext_vector_type(8))) short short8;
typedef __attribute__((ext_vector_type(4))) float floatx4;

#define GPTR(p) ((const __attribute__((address_space(1))) void*)(p))
#define LPTR(p) ((__attribute__((address_space(3))) void*)(p))

__device__ __forceinline__ unsigned short f2bf(float f) {
    unsigned int u = __float_as_uint(f);
    unsigned int r = (u + 0x7fffu + ((u >> 16) & 1u)) >> 16;  // RNE
    return (unsigned short)r;
}
__device__ __forceinline__ void unpack2(unsigned int u, float& a, float& b) {
    a = __uint_as_float(u << 16);
    b = __uint_as_float(u & 0xffff0000u);
}
__device__ __forceinline__ void unpack8(uint4 u, float* f) {
    unpack2(u.x, f[0], f[1]); unpack2(u.y, f[2], f[3]);
    unpack2(u.z, f[4], f[5]); unpack2(u.w, f[6], f[7]);
}
__device__ __forceinline__ void unpack4(uint2 u, float* f) {
    unpack2(u.x, f[0], f[1]); unpack2(u.y, f[2], f[3]);
}

// ---------------- x -> bf16 ----------------
__global__ __launch_bounds__(256) void xcast_kernel(
    const float* __restrict__ x, unsigned short* __restrict__ xb)
{
    size_t i = ((size_t)blockIdx.x * 256 + threadIdx.x) * 4;
    float4 v = *(const float4*)(x + i);
    uint2 p;
    p.x = (unsigned int)f2bf(v.x) | ((unsigned int)f2bf(v.y) << 16);
    p.y = (unsigned int)f2bf(v.z) | ((unsigned int)f2bf(v.w) << 16);
    *(uint2*)(xb + i) = p;
}

// ---------------- WcatT (bf16, [NCAT][256]) + bcat ----------------
__global__ __launch_bounds__(256) void wcat_kernel(
    const float* __restrict__ Wq, const float* __restrict__ Wk,
    const float* __restrict__ Wv, const float* __restrict__ Ws,
    const float* __restrict__ We,
    const float* __restrict__ bq, const float* __restrict__ bk,
    const float* __restrict__ bv, const float* __restrict__ bs,
    unsigned short* __restrict__ WcatT, float* __restrict__ bcat)
{
    int col = blockIdx.x;
    int kr  = threadIdx.x;
    float w = 0.f;
    if (col < 512) {
        int s = col >> 7, c = col & 127;
        const float* W = (s == 0) ? Wq : (s == 1) ? Wk : (s == 2) ? Wv : Ws;
        w = W[kr * OUT_SIZE + c];
    } else if (col < 576) {
        int d = col - 512;
        float a = 0.f;
        #pragma unroll 8
        for (int c = 0; c < OUT_SIZE; c++)
            a = fmaf(Wq[kr * OUT_SIZE + c], We[d * OUT_SIZE + c], a);
        w = a;
    }
    WcatT[(size_t)col * 256 + kr] = f2bf(w);
    if (kr == 0) {
        float b = 0.f;
        if (col < 512) {
            int s = col >> 7, c = col & 127;
            b = ((s == 0) ? bq : (s == 1) ? bk : (s == 2) ? bv : bs)[c];
        } else if (col < 576) {
            int d = col - 512;
            for (int c = 0; c < OUT_SIZE; c++)
                b = fmaf(bq[c], We[d * OUT_SIZE + c], b);
        }
        bcat[col] = b;
    }
}

// ---------------- MFMA mega GEMM, 128x128 tile, double-buffered ----------------
// grid (391, 5). seg y: 0=q(bf16) 1=k 2=v 3=sk->out(f32) 4=q2(bf16)
__global__ __launch_bounds__(256) void gemm_kernel(
    const unsigned short* __restrict__ xb,
    const unsigned short* __restrict__ WcatT,
    const float* __restrict__ bcat,
    unsigned short* __restrict__ qb16, unsigned short* __restrict__ kv16,
    float* __restrict__ outbuf, unsigned short* __restrict__ q2b16)
{
    __shared__ __align__(16) unsigned short Als[2][128 * 32];
    __shared__ __align__(16) unsigned short Bls[2][128 * 32];

    const int t      = threadIdx.x;
    const int wave   = t >> 6;
    const int lane   = t & 63;
    const int quad   = lane >> 4;
    const int l16    = lane & 15;
    const int wave_m = wave & 1;
    const int wave_n = wave >> 1;

    const int m0 = blockIdx.x * 128;
    const int n0 = blockIdx.y * 128;

    floatx4 acc[4][4];
    #pragma unroll
    for (int mt = 0; mt < 4; mt++)
        #pragma unroll
        for (int nt = 0; nt < 4; nt++)
            acc[mt][nt] = (floatx4){0.f, 0.f, 0.f, 0.f};

#define STAGE(K0, BUF)                                                              \
    {                                                                               \
        _Pragma("unroll")                                                           \
        for (int r = 0; r < 2; r++) {                                               \
            int idx  = r * 256 + t;                                                 \
            int row  = idx >> 2;                                                    \
            int c8   = idx & 3;                                                     \
            int grow = m0 + row;                                                    \
            if (grow >= N_NODES) grow = N_NODES - 1;                                \
            const unsigned short* ga = xb + (size_t)grow * IN_SIZE + (K0) + c8 * 8; \
            __builtin_amdgcn_global_load_lds(GPTR(ga),                              \
                LPTR(Als[BUF] + (size_t)(r * 256 + wave * 64) * 8), 16, 0, 0);      \
            const unsigned short* gb = WcatT + (size_t)(n0 + row) * 256 + (K0) + c8 * 8; \
            __builtin_amdgcn_global_load_lds(GPTR(gb),                              \
                LPTR(Bls[BUF] + (size_t)(r * 256 + wave * 64) * 8), 16, 0, 0);      \
        }                                                                           \
    }

    STAGE(0, 0)
    #pragma unroll
    for (int kk = 0; kk < 8; kk++) {
        __syncthreads();
        if (kk + 1 < 8) STAGE((kk + 1) * 32, (kk + 1) & 1)
        const unsigned short* Ab = Als[kk & 1];
        const unsigned short* Bb = Bls[kk & 1];
        short8 af[4], bf[4];
        #pragma unroll
        for (int mt = 0; mt < 4; mt++)
            af[mt] = *(const short8*)(Ab + (size_t)(wave_m * 64 + mt * 16 + l16) * 32 + quad * 8);
        #pragma unroll
        for (int nt = 0; nt < 4; nt++)
            bf[nt] = *(const short8*)(Bb + (size_t)(wave_n * 64 + nt * 16 + l16) * 32 + quad * 8);
        #pragma unroll
        for (int mt = 0; mt < 4; mt++)
            #pragma unroll
            for (int nt = 0; nt < 4; nt++)
                acc[mt][nt] = __builtin_amdgcn_mfma_f32_16x16x32_bf16(af[mt], bf[nt], acc[mt][nt], 0, 0, 0);
    }
#undef STAGE

    const int seg = blockIdx.y;
    #pragma unroll
    for (int mt = 0; mt < 4; mt++) {
        #pragma unroll
        for (int r = 0; r < 4; r++) {
            int row = m0 + wave_m * 64 + mt * 16 + quad * 4 + r;
            if (row >= N_NODES) continue;
            #pragma unroll
            for (int nt = 0; nt < 4; nt++) {
                int c = n0 + wave_n * 64 + nt * 16 + l16;
                float val = acc[mt][nt][r] + bcat[c];
                if (seg == 0)      qb16[(size_t)row * OUT_SIZE + c] = f2bf(val);
                else if (seg == 1) kv16[(size_t)row * 256 + (c - 128)] = f2bf(val);
                else if (seg == 2) kv16[(size_t)row * 256 + 128 + (c - 256)] = f2bf(val);
                else if (seg == 3) outbuf[(size_t)row * OUT_SIZE + (c - 384)] = val;
                else if (c < 576)  q2b16[(size_t)row * EDGE_DIM + (c - 512)] = f2bf(val);
            }
        }
    }
}

// ---------------- CSR build ----------------
__global__ __launch_bounds__(256) void hist_kernel(
    const int* __restrict__ ei, int* __restrict__ counts)
{
    int e = blockIdx.x * 256 + threadIdx.x;
    if (e >= N_EDGES) return;
    atomicAdd(&counts[ei[N_EDGES + e]], 1);
}

__global__ __launch_bounds__(SCAN_B) void scan1_kernel(
    const int* __restrict__ counts, int* __restrict__ incl, int* __restrict__ bsum)
{
    __shared__ int tmp[SCAN_B];
    int i = blockIdx.x * SCAN_B + threadIdx.x;
    int val = (i < N_NODES) ? counts[i] : 0;
    tmp[threadIdx.x] = val;
    __syncthreads();
    for (int off = 1; off < SCAN_B; off <<= 1) {
        int t = (threadIdx.x >= off) ? tmp[threadIdx.x - off] : 0;
        __syncthreads();
        tmp[threadIdx.x] += t;
        __syncthreads();
    }
    if (i < N_NODES) incl[i] = tmp[threadIdx.x];
    if (threadIdx.x == SCAN_B - 1) bsum[blockIdx.x] = tmp[SCAN_B - 1];
}

__global__ __launch_bounds__(SCAN_B) void scan2_kernel(int* __restrict__ bsum)
{
    __shared__ int tmp[SCAN_B];
    int val = (threadIdx.x < NBLK) ? bsum[threadIdx.x] : 0;
    tmp[threadIdx.x] = val;
    __syncthreads();
    for (int off = 1; off < SCAN_B; off <<= 1) {
        int t = (threadIdx.x >= off) ? tmp[threadIdx.x - off] : 0;
        __syncthreads();
        tmp[threadIdx.x] += t;
        __syncthreads();
    }
    if (threadIdx.x < NBLK) bsum[threadIdx.x] = tmp[threadIdx.x];
}

__global__ __launch_bounds__(SCAN_B) void scan3_kernel(
    const int* __restrict__ incl, const int* __restrict__ bsum,
    const int* __restrict__ counts, int* __restrict__ rowptr, int* __restrict__ cursor)
{
    int i = blockIdx.x * SCAN_B + threadIdx.x;
    if (i >= N_NODES) return;
    int off = (blockIdx.x == 0) ? 0 : bsum[blockIdx.x - 1];
    int inc = incl[i] + off;
    rowptr[i + 1] = inc;
    cursor[i] = inc - counts[i];
    if (i == 0) rowptr[0] = 0;
}

// ---------------- pos: edge -> CSR slot, src scatter ----------------
__global__ __launch_bounds__(256) void pos_kernel(
    const int* __restrict__ ei, int* __restrict__ cursor,
    int* __restrict__ pos, int* __restrict__ csr_src)
{
    int e = blockIdx.x * 256 + threadIdx.x;
    if (e >= N_EDGES) return;
    int dst = ei[N_EDGES + e];
    int p = atomicAdd(&cursor[dst], 1);
    pos[e] = p;
    csr_src[p] = ei[e];
}

// ---------------- perm: counting-sorted bf16 edge_attr, wave per 4 edges ----------------
__global__ __launch_bounds__(256) void perm_kernel(
    const float* __restrict__ ea, const int* __restrict__ pos,
    unsigned short* __restrict__ eperm)
{
    int w    = (blockIdx.x * 256 + threadIdx.x) >> 6;
    int lane = threadIdx.x & 63;
    int grp  = lane >> 4;
    int l16  = lane & 15;
    int e = w * 4 + grp;
    float4 f = ((const float4*)(ea + (size_t)e * EDGE_DIM))[l16];
    uint2 u;
    u.x = (unsigned int)f2bf(f.x) | ((unsigned int)f2bf(f.y) << 16);
    u.y = (unsigned int)f2bf(f.z) | ((unsigned int)f2bf(f.w) << 16);
    int p = pos[e];
    ((uint2*)(eperm + (size_t)p * EDGE_DIM))[l16] = u;
}

// ---------------- fused: wave per node, 4 edges in parallel (16 lanes/edge) ----------------
__global__ __launch_bounds__(256) void fused_kernel(
    const int* __restrict__ rowptr, const int* __restrict__ csr_src,
    const unsigned short* __restrict__ qb16,   // [N][128]
    const unsigned short* __restrict__ kv16,   // [N][256]: k|v
    const unsigned short* __restrict__ q2b,    // [N][64]
    const unsigned short* __restrict__ eperm,  // [E][64] csr-ordered
    const float* __restrict__ We, const float* __restrict__ be,
    float* __restrict__ out)                   // holds skip, rewritten
{
    int node = blockIdx.x * 4 + (threadIdx.x >> 6);
    if (node >= N_NODES) return;
    int lane = threadIdx.x & 63;
    int grp  = lane >> 4;
    int l16  = lane & 15;
    int beg = rowptr[node], end = rowptr[node + 1];

    float q8[8], q24[4];
    unpack8(((const uint4*)(qb16 + (size_t)node * OUT_SIZE))[l16], q8);
    unpack4(((const uint2*)(q2b + (size_t)node * EDGE_DIM))[l16], q24);
    float4 beA = ((const float4*)be)[l16 * 2];
    float4 beB = ((const float4*)be)[l16 * 2 + 1];

    // qb = dot(q, be): per-lane partial over 8 dims, reduce over 16 lanes
    float qbv = q8[0] * beA.x + q8[1] * beA.y + q8[2] * beA.z + q8[3] * beA.w
              + q8[4] * beB.x + q8[5] * beB.y + q8[6] * beB.z + q8[7] * beB.w;
    #pragma unroll
    for (int off = 1; off < 16; off <<= 1) qbv += __shfl_xor(qbv, off);

    const float scale = 0.08838834764831845f;  // 1/sqrt(128)
    float l = 0.f;
    float ax[8] = {0.f, 0.f, 0.f, 0.f, 0.f, 0.f, 0.f, 0.f};
    float a2[4] = {0.f, 0.f, 0.f, 0.f};

    for (int i = beg; i < end; i += 4) {
        int idx = i + grp;
        bool valid = idx < end;
        int ic = valid ? idx : end - 1;
        int s = csr_src[ic];
        const uint4* kvrow = (const uint4*)(kv16 + (size_t)s * 256);
        uint4 ku = kvrow[l16];
        uint4 vu = kvrow[16 + l16];
        uint2 eu = ((const uint2*)(eperm + (size_t)ic * EDGE_DIM))[l16];
        float k8[8], v8[8], e4[4];
        unpack8(ku, k8);
        unpack8(vu, v8);
        unpack4(eu, e4);
        float p = q8[0] * k8[0] + q8[1] * k8[1] + q8[2] * k8[2] + q8[3] * k8[3]
                + q8[4] * k8[4] + q8[5] * k8[5] + q8[6] * k8[6] + q8[7] * k8[7]
                + q24[0] * e4[0] + q24[1] * e4[1] + q24[2] * e4[2] + q24[3] * e4[3];
        #pragma unroll
        for (int off = 1; off < 16; off <<= 1) p += __shfl_xor(p, off);
        float pe = valid ? __expf((p + qbv) * scale) : 0.f;
        l += pe;
        #pragma unroll
        for (int j = 0; j < 8; j++) ax[j] = fmaf(pe, v8[j], ax[j]);
        #pragma unroll
        for (int j = 0; j < 4; j++) a2[j] = fmaf(pe, e4[j], a2[j]);
    }

    // combine 4 edge-groups (dims align across groups)
    l += __shfl_xor(l, 16); l += __shfl_xor(l, 32);
    #pragma unroll
    for (int j = 0; j < 8; j++) {
        ax[j] += __shfl_xor(ax[j], 16); ax[j] += __shfl_xor(ax[j], 32);
    }
    #pragma unroll
    for (int j = 0; j < 4; j++) {
        a2[j] += __shfl_xor(a2[j], 16); a2[j] += __shfl_xor(a2[j], 32);
    }

    float inv  = 1.f / (l + 1e-16f);
    float aggA = l * inv;
    #pragma unroll
    for (int j = 0; j < 8; j++) ax[j] *= inv;
    #pragma unroll
    for (int j = 0; j < 4; j++) a2[j] *= inv;

    // We epilogue: quad handles d = grp*16 + dd
    float o8[8] = {0.f, 0.f, 0.f, 0.f, 0.f, 0.f, 0.f, 0.f};
    #pragma unroll
    for (int dd = 0; dd < 16; dd++) {
        int d = grp * 16 + dd;
        float g = __shfl(a2[dd & 3], d >> 2);
        const float4* wr = (const float4*)(We + (size_t)d * OUT_SIZE + l16 * 8);
        float4 wA = wr[0], wB = wr[1];
        o8[0] = fmaf(g, wA.x, o8[0]); o8[1] = fmaf(g, wA.y, o8[1]);
        o8[2] = fmaf(g, wA.z, o8[2]); o8[3] = fmaf(g, wA.w, o8[3]);
        o8[4] = fmaf(g, wB.x, o8[4]); o8[5] = fmaf(g, wB.y, o8[5]);
        o8[6] = fmaf(g, wB.z, o8[6]); o8[7] = fmaf(g, wB.w, o8[7]);
    }
    #pragma unroll
    for (int j = 0; j < 8; j++) {
        o8[j] += __shfl_xor(o8[j], 16); o8[j] += __shfl_xor(o8[j], 32);
    }

    if (grp == 0) {
        const float4* sk = (const float4*)(out + (size_t)node * OUT_SIZE + l16 * 8);
        float4 skA = sk[0], skB = sk[1];
        float be8[8] = {beA.x, beA.y, beA.z, beA.w, beB.x, beB.y, beB.z, beB.w};
        float sk8[8] = {skA.x, skA.y, skA.z, skA.w, skB.x, skB.y, skB.z, skB.w};
        float r[8];
        #pragma unroll
        for (int j = 0; j < 8; j++) {
            float v = o8[j] + ax[j] + aggA * be8[j] + sk8[j];
            r[j] = (v > 0.f) ? v : (__expf(v) - 1.f);
        }
        float4* d4 = (float4*)(out + (size_t)node * OUT_SIZE + l16 * 8);
        d4[0] = make_float4(r[0], r[1], r[2], r[3]);
        d4[1] = make_float4(r[4], r[5], r[6], r[7]);
    }
}

extern "C" void kernel_launch(void* const* d_in, const int* in_sizes, int n_in,
                              void* d_out, int out_size, void* d_ws, size_t ws_size,
                              hipStream_t stream) {
    const float* x   = (const float*)d_in[0];
    const int*   ei  = (const int*)d_in[1];
    const float* ea  = (const float*)d_in[2];
    const float* Wq  = (const float*)d_in[3];
    const float* bq  = (const float*)d_in[4];
    const float* Wk  = (const float*)d_in[5];
    const float* bk  = (const float*)d_in[6];
    const float* Wv  = (const float*)d_in[7];
    const float* bv  = (const float*)d_in[8];
    const float* We  = (const float*)d_in[9];
    const float* be  = (const float*)d_in[10];
    const float* Ws  = (const float*)d_in[11];
    const float* bs  = (const float*)d_in[12];
    float* out = (float*)d_out;

    // workspace layout (~155 MB): eperm overlaps xb (xb dead after gemm)
    char* base = (char*)d_ws;
    size_t off = 0;
    auto alloc = [&](size_t bytes) { char* p = base + off; off = (off + bytes + 255) & ~(size_t)255; return p; };
    unsigned short* qb16  = (unsigned short*)alloc((size_t)N_NODES * OUT_SIZE * 2);
    unsigned short* q2b16 = (unsigned short*)alloc((size_t)N_NODES * EDGE_DIM * 2);
    unsigned short* kv16  = (unsigned short*)alloc((size_t)N_NODES * 256 * 2);
    unsigned short* WcatT = (unsigned short*)alloc((size_t)NCAT * 256 * 2);
    float* bcat  = (float*)alloc(NCAT * 4);
    int* counts  = (int*)alloc((size_t)N_NODES * 4);
    int* incl    = (int*)alloc((size_t)N_NODES * 4);
    int* bsum    = (int*)alloc(256 * 4);
    int* rowptr  = (int*)alloc((size_t)(N_NODES + 1) * 4);
    int* cursor  = (int*)alloc((size_t)N_NODES * 4);
    int* pos     = (int*)alloc((size_t)N_EDGES * 4);
    int* csr_src = (int*)alloc((size_t)N_EDGES * 4);
    unsigned short* xb    = (unsigned short*)alloc((size_t)N_NODES * IN_SIZE * 2);
    unsigned short* eperm = xb;  // overlap: perm runs after gemm
    (void)ws_size;

    hipMemsetAsync(counts, 0, (size_t)N_NODES * sizeof(int), stream);

    // CSR build
    hist_kernel<<<(N_EDGES + 255) / 256, 256, 0, stream>>>(ei, counts);
    scan1_kernel<<<NBLK, SCAN_B, 0, stream>>>(counts, incl, bsum);
    scan2_kernel<<<1, SCAN_B, 0, stream>>>(bsum);
    scan3_kernel<<<NBLK, SCAN_B, 0, stream>>>(incl, bsum, counts, rowptr, cursor);
    pos_kernel<<<(N_EDGES + 255) / 256, 256, 0, stream>>>(ei, cursor, pos, csr_src);

    // bf16 conversions / weights, then GEMM (consumes xb)
    xcast_kernel<<<(N_NODES * IN_SIZE / 4 + 255) / 256, 256, 0, stream>>>(x, xb);
    wcat_kernel<<<NCAT, 256, 0, stream>>>(Wq, Wk, Wv, Ws, We, bq, bk, bv, bs, WcatT, bcat);
    dim3 gG((N_NODES + 127) / 128, 5);
    gemm_kernel<<<gG, 256, 0, stream>>>(xb, WcatT, bcat, qb16, kv16, out, q2b16);

    // edge-attr counting sort (bf16) into eperm (over xb)
    perm_kernel<<<N_EDGES / 16, 256, 0, stream>>>(ea, pos, eperm);

    // fused edge phase + epilogue
    fused_kernel<<<(N_NODES + 3) / 4, 256, 0, stream>>>(
        rowptr, csr_src, qb16, kv16, q2b16, eperm, We, be, out);
}